// Round 5
// baseline (35773.804 us; speedup 1.0000x reference)
//
#include <hip/hip_runtime.h>
#include <math.h>

#define BB    32
#define TT    100
#define INPUT 132
#define HH    1024
#define GG    4096
#define OUTC  132
#define SW    96                    // state row width: 3 cells * 32 batch
#define MH    4194304               // halves per 4096x1024 matrix

typedef _Float16 h2_t __attribute__((ext_vector_type(2)));
typedef _Float16 h4_t __attribute__((ext_vector_type(4)));

__device__ __forceinline__ float fdot2(unsigned int w, unsigned int h, float acc) {
    union { unsigned int u; h2_t h2; } uw, uh;
    uw.u = w; uh.u = h;
    return __builtin_amdgcn_fdot2(uw.h2, uh.h2, acc, false);
}
__device__ __forceinline__ float dot2x4(uint4 wv, const unsigned int* hp, float a) {
    a = fdot2(wv.x, hp[0], a);
    a = fdot2(wv.y, hp[1], a);
    a = fdot2(wv.z, hp[2], a);
    a = fdot2(wv.w, hp[3], a);
    return a;
}

// ---------------------------------------------------------------------------
// fp32 -> fp16 weight conversion (n multiple of 4)
// ---------------------------------------------------------------------------
__global__ __launch_bounds__(256)
void conv_kernel(const float* __restrict__ src, _Float16* __restrict__ dst, int n4)
{
    for (int i = blockIdx.x * 256 + threadIdx.x; i < n4; i += gridDim.x * 256) {
        const float4 v = ((const float4*)src)[i];
        h4_t o; o.x = (_Float16)v.x; o.y = (_Float16)v.y;
        o.z = (_Float16)v.z; o.w = (_Float16)v.w;
        ((h4_t*)dst)[i] = o;
    }
}

// ---------------------------------------------------------------------------
// W_comb[j][k] = sum_m W_ih1[j][m] * W_dec[m][k]  (4096x1024), fp16 output
// ---------------------------------------------------------------------------
__global__ __launch_bounds__(256)
void comb_kernel(const float* __restrict__ Wih1, const float* __restrict__ Wdec,
                 _Float16* __restrict__ Wcomb16)
{
    __shared__ float wiT[INPUT][64];
    __shared__ float wd[INPUT][64];
    const int tid = threadIdx.x;
    const int jt = (blockIdx.x >> 4) << 6;
    const int kt = (blockIdx.x & 15) << 6;

    for (int i = tid; i < 64 * INPUT; i += 256) {
        const int j = i / INPUT, m = i % INPUT;
        wiT[m][j] = Wih1[(size_t)(jt + j) * INPUT + m];
    }
    for (int i = tid; i < INPUT * 64; i += 256) {
        const int m = i >> 6, k = i & 63;
        wd[m][k] = Wdec[(size_t)m * HH + kt + k];
    }
    __syncthreads();

    const int jl = (tid >> 4) << 2;
    const int kl = (tid & 15) << 2;
    float a[4][4];
#pragma unroll
    for (int x = 0; x < 4; ++x)
#pragma unroll
        for (int y = 0; y < 4; ++y) a[x][y] = 0.f;

    for (int m = 0; m < INPUT; ++m) {
        const float4 wj = *(const float4*)&wiT[m][jl];
        const float4 wk = *(const float4*)&wd[m][kl];
        a[0][0] += wj.x * wk.x; a[0][1] += wj.x * wk.y; a[0][2] += wj.x * wk.z; a[0][3] += wj.x * wk.w;
        a[1][0] += wj.y * wk.x; a[1][1] += wj.y * wk.y; a[1][2] += wj.y * wk.z; a[1][3] += wj.y * wk.w;
        a[2][0] += wj.z * wk.x; a[2][1] += wj.z * wk.y; a[2][2] += wj.z * wk.z; a[2][3] += wj.z * wk.w;
        a[3][0] += wj.w * wk.x; a[3][1] += wj.w * wk.y; a[3][2] += wj.w * wk.z; a[3][3] += wj.w * wk.w;
    }
#pragma unroll
    for (int jj = 0; jj < 4; ++jj) {
        h4_t v; v.x = (_Float16)a[jj][0]; v.y = (_Float16)a[jj][1];
        v.z = (_Float16)a[jj][2]; v.w = (_Float16)a[jj][3];
        *(h4_t*)&Wcomb16[(size_t)(jt + jl + jj) * HH + kt + kl] = v;
    }
}

// ---------------------------------------------------------------------------
// Bias precompute (fp32)
// ---------------------------------------------------------------------------
__global__ __launch_bounds__(256)
void bias_kernel(const float* __restrict__ Wih1, const float* __restrict__ bdec,
                 const float* __restrict__ bih1, const float* __restrict__ bhh1,
                 const float* __restrict__ bih2, const float* __restrict__ bhh2,
                 const float* __restrict__ bih3, const float* __restrict__ bhh3,
                 float* __restrict__ bc_gt, float* __restrict__ bc_ng,
                 float* __restrict__ bc2, float* __restrict__ bc3)
{
    const int j = blockIdx.x * 256 + threadIdx.x;
    if (j >= GG) return;
    const float s1 = bih1[j] + bhh1[j];
    float cb = 0.f;
    for (int m = 0; m < INPUT; ++m) cb += Wih1[(size_t)j * INPUT + m] * bdec[m];
    bc_gt[j] = s1;
    bc_ng[j] = s1 + cb;
    bc2[j] = bih2[j] + bhh2[j];
    bc3[j] = bih3[j] + bhh3[j];
}

// ---------------------------------------------------------------------------
// One timestep. grid 1024: WG owns unit u=wg. block 256 = 32 b x 8 k-slices
// of 128. Weights fp16 (W16: 6 matrices contiguous; order Whh1,Wih2,Whh2,
// Wih3,Whh3,Wcomb). h stored as packed fp16 pairs hT16[k/2][96] (uint words);
// c stays fp32. v_dot2_f32_f16 accumulates in fp32.
// __launch_bounds__(256,4): 4 blocks/CU (empirical blocks-semantics) ->
// 128 VGPR cap, grid covers chip in one round.
// ---------------------------------------------------------------------------
template <bool USE_GT>
__global__ __launch_bounds__(256, 4)
void phase_kernel(const float* __restrict__ seq, const float* __restrict__ Wih1f,
                  const _Float16* __restrict__ W16,
                  const _Float16* __restrict__ Wdec16, const float* __restrict__ bdec,
                  const float* __restrict__ bc_gt, const float* __restrict__ bc_ng,
                  const float* __restrict__ bc2, const float* __restrict__ bc3,
                  const unsigned int* __restrict__ h16r, _Float16* __restrict__ h16w,
                  float* __restrict__ cstT, float* __restrict__ outp, int t)
{
    __shared__ float red[4][12][BB];
    __shared__ float dpart[4][BB];

    const int tid = threadIdx.x;
    const int wg  = blockIdx.x;          // hidden unit u
    const int b   = tid & 31;
    const int cg  = tid >> 5;            // k-slice 0..7
    const int k0  = cg << 7;             // [k0, k0+128)

    const bool do_gates = (t < TT);
    const bool do_dec   = (t >= 1) && (wg < OUTC);

    float acc[12];
#pragma unroll
    for (int i = 0; i < 12; ++i) acc[i] = 0.f;
    float dec = 0.f;

    if (do_gates) {
        if (USE_GT) {
            // x-part (fp32): rows g*1024+u of Wih1, x = seq[b, t, :]
            for (int kq = cg; kq < 33; kq += 8) {
                const float4 xq = *(const float4*)&seq[(size_t)b * (TT * INPUT) +
                                                       (size_t)t * INPUT + (kq << 2)];
#pragma unroll
                for (int g = 0; g < 4; ++g) {
                    const float4 w = *(const float4*)&Wih1f[((g << 10) + wg) * INPUT + (kq << 2)];
                    acc[g] += w.x * xq.x + w.y * xq.y + w.z * xq.z + w.w * xq.w;
                }
            }
        }

        // loop-invariant uint4 row pointers (offset in halves)
        const uint4* pw[4][6];
        const uint4* pd = (const uint4*)(Wdec16 + (wg << 10) + k0);
#pragma unroll
        for (int g = 0; g < 4; ++g) {
            const int ro = ((((g << 10) + wg) << 10) + k0);
#pragma unroll
            for (int m = 0; m < 6; ++m)
                pw[g][m] = (const uint4*)(W16 + (size_t)m * MH + ro);
        }
        const unsigned int* hb = h16r + (size_t)(k0 >> 1) * SW + b;

#pragma unroll 2
        for (int it = 0; it < 16; ++it) {
            unsigned int hp0[4], hp1[4], hp2[4];
            const unsigned int* hq = hb + (it << 2) * SW;
#pragma unroll
            for (int p = 0; p < 4; ++p) {
                hp0[p] = hq[p * SW];
                hp1[p] = hq[p * SW + 32];
                hp2[p] = hq[p * SW + 64];
            }
#pragma unroll
            for (int g = 0; g < 4; ++g) {
                acc[g]     = dot2x4(pw[g][0][it], hp0, acc[g]);      // Whh1 @ h0
                if (!USE_GT)
                    acc[g] = dot2x4(pw[g][5][it], hp2, acc[g]);      // Wcomb @ h2
                acc[4 + g] = dot2x4(pw[g][1][it], hp0, acc[4 + g]);  // Wih2 @ h0
                acc[4 + g] = dot2x4(pw[g][2][it], hp1, acc[4 + g]);  // Whh2 @ h1
                acc[8 + g] = dot2x4(pw[g][3][it], hp1, acc[8 + g]);  // Wih3 @ h1
                acc[8 + g] = dot2x4(pw[g][4][it], hp2, acc[8 + g]);  // Whh3 @ h2
            }
            if (do_dec) dec = dot2x4(pd[it], hp2, dec);
        }
    } else if (do_dec) {
        const uint4* pd = (const uint4*)(Wdec16 + (wg << 10) + k0);
        const unsigned int* hb = h16r + (size_t)(k0 >> 1) * SW + b;
#pragma unroll 2
        for (int it = 0; it < 16; ++it) {
            unsigned int hp2[4];
            const unsigned int* hq = hb + (it << 2) * SW;
#pragma unroll
            for (int p = 0; p < 4; ++p) hp2[p] = hq[p * SW + 64];
            dec = dot2x4(pd[it], hp2, dec);
        }
    }

    // pre-reduce k-slice pairs within each wave (lanes l, l^32: cg pairs)
    if (do_gates) {
#pragma unroll
        for (int i = 0; i < 12; ++i) acc[i] += __shfl_xor(acc[i], 32);
        if (!(cg & 1)) {
            const int s = cg >> 1;
#pragma unroll
            for (int i = 0; i < 12; ++i) red[s][i][b] = acc[i];
        }
    }
    if (do_dec) {
        dec += __shfl_xor(dec, 32);
        if (!(cg & 1)) dpart[cg >> 1][b] = dec;
    }
    __syncthreads();

    if (do_gates && tid < 96) {
        const int cell = tid >> 5;
        const int bb = tid & 31;
        float gate[4];
#pragma unroll
        for (int g = 0; g < 4; ++g) {
            float s = 0.f;
#pragma unroll
            for (int sl = 0; sl < 4; ++sl) s += red[sl][cell * 4 + g][bb];
            gate[g] = s;
        }
        const float* bias = (cell == 0) ? (USE_GT ? bc_gt : bc_ng)
                                        : ((cell == 1) ? bc2 : bc3);
        const float gi = gate[0] + bias[wg];
        const float gf = gate[1] + bias[HH + wg];
        const float gg = gate[2] + bias[2 * HH + wg];
        const float go = gate[3] + bias[3 * HH + wg];
        const int si = wg * SW + cell * 32 + bb;
        const float cold = cstT[si];
        const float is = 1.f / (1.f + expf(-gi));
        const float fs = 1.f / (1.f + expf(-gf));
        const float os = 1.f / (1.f + expf(-go));
        const float cn = fs * cold + is * tanhf(gg);
        const float hn = os * tanhf(cn);
        cstT[si] = cn;
        // packed-pair fp16 h: word (u>>1), half (u&1)
        h16w[(((wg >> 1) * SW) + cell * 32 + bb) * 2 + (wg & 1)] = (_Float16)hn;
    }
    if (do_dec && tid < BB) {
        float s = 0.f;
#pragma unroll
        for (int sl = 0; sl < 4; ++sl) s += dpart[sl][tid];
        outp[(size_t)tid * (TT * OUTC) + (size_t)(t - 1) * OUTC + wg] = s + bdec[wg];
    }
}

// ---------------------------------------------------------------------------
extern "C" void kernel_launch(void* const* d_in, const int* in_sizes, int n_in,
                              void* d_out, int out_size, void* d_ws, size_t ws_size,
                              hipStream_t stream)
{
    const float* seq  = (const float*)d_in[0];
    const float* Wih1 = (const float*)d_in[1];
    const float* Whh1 = (const float*)d_in[2];
    const float* bih1 = (const float*)d_in[3];
    const float* bhh1 = (const float*)d_in[4];
    const float* Wih2 = (const float*)d_in[5];
    const float* Whh2 = (const float*)d_in[6];
    const float* bih2 = (const float*)d_in[7];
    const float* bhh2 = (const float*)d_in[8];
    const float* Wih3 = (const float*)d_in[9];
    const float* Whh3 = (const float*)d_in[10];
    const float* bih3 = (const float*)d_in[11];
    const float* bhh3 = (const float*)d_in[12];
    const float* Wdec = (const float*)d_in[13];
    const float* bdec = (const float*)d_in[14];
    float* outp = (float*)d_out;
    char* wsb   = (char*)d_ws;

    // ws layout (bytes)
    _Float16* W16    = (_Float16*)(wsb);                       // 6 x 8,388,608
    _Float16* Wdec16 = (_Float16*)(wsb + 50331648);            // 270,336
    float*    bc_gt  = (float*)(wsb + 50601984);               // 4 x 16,384
    float*    bc_ng  = bc_gt + GG;
    float*    bc2    = bc_ng + GG;
    float*    bc3    = bc2 + GG;
    char*     h16b   = wsb + 50667520;                         // 2 x 196,608
    float*    cstT   = (float*)(wsb + 51060736);               // 393,216

    // zero h ping-pong (fp16 0x0000) + c state
    hipMemsetAsync(h16b, 0, 2 * 196608 + 393216, stream);

    conv_kernel<<<dim3(2048), dim3(256), 0, stream>>>(Whh1, W16 + 0 * (size_t)MH, MH / 4);
    conv_kernel<<<dim3(2048), dim3(256), 0, stream>>>(Wih2, W16 + 1 * (size_t)MH, MH / 4);
    conv_kernel<<<dim3(2048), dim3(256), 0, stream>>>(Whh2, W16 + 2 * (size_t)MH, MH / 4);
    conv_kernel<<<dim3(2048), dim3(256), 0, stream>>>(Wih3, W16 + 3 * (size_t)MH, MH / 4);
    conv_kernel<<<dim3(2048), dim3(256), 0, stream>>>(Whh3, W16 + 4 * (size_t)MH, MH / 4);
    conv_kernel<<<dim3(132),  dim3(256), 0, stream>>>(Wdec, Wdec16, (OUTC * HH) / 4);
    comb_kernel<<<dim3(1024), dim3(256), 0, stream>>>(Wih1, Wdec, W16 + 5 * (size_t)MH);
    bias_kernel<<<dim3(16), dim3(256), 0, stream>>>(Wih1, bdec, bih1, bhh1, bih2, bhh2,
                                                    bih3, bhh3, bc_gt, bc_ng, bc2, bc3);

    for (int t = 0; t <= TT; ++t) {
        const unsigned int* hr = (const unsigned int*)(h16b + (t & 1) * 196608);
        _Float16* hw = (_Float16*)(h16b + ((t + 1) & 1) * 196608);
        const bool gt = (t % 10) < 5;
        if (gt)
            phase_kernel<true><<<dim3(1024), dim3(256), 0, stream>>>(
                seq, Wih1, W16, Wdec16, bdec, bc_gt, bc_ng, bc2, bc3,
                hr, hw, cstT, outp, t);
        else
            phase_kernel<false><<<dim3(1024), dim3(256), 0, stream>>>(
                seq, Wih1, W16, Wdec16, bdec, bc_gt, bc_ng, bc2, bc3,
                hr, hw, cstT, outp, t);
    }
}

// Round 6
// 33331.009 us; speedup vs baseline: 1.0733x; 1.0733x over previous
//
#include <hip/hip_runtime.h>
#include <math.h>

#define BB    32
#define TT    100
#define INPUT 132
#define HH    1024
#define GG    4096
#define OUTC  132
#define SW    96                    // state row width: 3 cells * 32 batch
#define MH    4194304               // halves per 4096x1024 matrix

typedef _Float16 h2_t __attribute__((ext_vector_type(2)));
typedef _Float16 h4_t __attribute__((ext_vector_type(4)));

__device__ __forceinline__ float fdot2(unsigned int w, unsigned int h, float acc) {
    union { unsigned int u; h2_t h2; } uw, uh;
    uw.u = w; uh.u = h;
    return __builtin_amdgcn_fdot2(uw.h2, uh.h2, acc, false);
}
// weight uint4 (8 halves) dot packed-h words
__device__ __forceinline__ float dot2x4(uint4 wv, const unsigned int* hp, float a) {
    a = fdot2(wv.x, hp[0], a);
    a = fdot2(wv.y, hp[1], a);
    a = fdot2(wv.z, hp[2], a);
    a = fdot2(wv.w, hp[3], a);
    return a;
}
// SGPR-base + VGPR byte-offset load (round-4 proven addressing: keeps weight
// bases out of VGPRs; `boff` small enough for the 13-bit imm to fold it*16)
__device__ __forceinline__ uint4 ldw16(const _Float16* __restrict__ p, int boff) {
    return *(const uint4*)((const char*)p + boff);
}

// ---------------------------------------------------------------------------
// fp32 -> fp16 weight conversion (n4 = n/4)
// ---------------------------------------------------------------------------
__global__ __launch_bounds__(256)
void conv_kernel(const float* __restrict__ src, _Float16* __restrict__ dst, int n4)
{
    for (int i = blockIdx.x * 256 + threadIdx.x; i < n4; i += gridDim.x * 256) {
        const float4 v = ((const float4*)src)[i];
        h4_t o; o.x = (_Float16)v.x; o.y = (_Float16)v.y;
        o.z = (_Float16)v.z; o.w = (_Float16)v.w;
        ((h4_t*)dst)[i] = o;
    }
}

// ---------------------------------------------------------------------------
// W_comb[j][k] = sum_m W_ih1[j][m] * W_dec[m][k]  (4096x1024), fp16 output
// ---------------------------------------------------------------------------
__global__ __launch_bounds__(256)
void comb_kernel(const float* __restrict__ Wih1, const float* __restrict__ Wdec,
                 _Float16* __restrict__ Wcomb16)
{
    __shared__ float wiT[INPUT][64];
    __shared__ float wd[INPUT][64];
    const int tid = threadIdx.x;
    const int jt = (blockIdx.x >> 4) << 6;
    const int kt = (blockIdx.x & 15) << 6;

    for (int i = tid; i < 64 * INPUT; i += 256) {
        const int j = i / INPUT, m = i % INPUT;
        wiT[m][j] = Wih1[(size_t)(jt + j) * INPUT + m];
    }
    for (int i = tid; i < INPUT * 64; i += 256) {
        const int m = i >> 6, k = i & 63;
        wd[m][k] = Wdec[(size_t)m * HH + kt + k];
    }
    __syncthreads();

    const int jl = (tid >> 4) << 2;
    const int kl = (tid & 15) << 2;
    float a[4][4];
#pragma unroll
    for (int x = 0; x < 4; ++x)
#pragma unroll
        for (int y = 0; y < 4; ++y) a[x][y] = 0.f;

    for (int m = 0; m < INPUT; ++m) {
        const float4 wj = *(const float4*)&wiT[m][jl];
        const float4 wk = *(const float4*)&wd[m][kl];
        a[0][0] += wj.x * wk.x; a[0][1] += wj.x * wk.y; a[0][2] += wj.x * wk.z; a[0][3] += wj.x * wk.w;
        a[1][0] += wj.y * wk.x; a[1][1] += wj.y * wk.y; a[1][2] += wj.y * wk.z; a[1][3] += wj.y * wk.w;
        a[2][0] += wj.z * wk.x; a[2][1] += wj.z * wk.y; a[2][2] += wj.z * wk.z; a[2][3] += wj.z * wk.w;
        a[3][0] += wj.w * wk.x; a[3][1] += wj.w * wk.y; a[3][2] += wj.w * wk.z; a[3][3] += wj.w * wk.w;
    }
#pragma unroll
    for (int jj = 0; jj < 4; ++jj) {
        h4_t v; v.x = (_Float16)a[jj][0]; v.y = (_Float16)a[jj][1];
        v.z = (_Float16)a[jj][2]; v.w = (_Float16)a[jj][3];
        *(h4_t*)&Wcomb16[(size_t)(jt + jl + jj) * HH + kt + kl] = v;
    }
}

// ---------------------------------------------------------------------------
// Bias precompute (fp32)
// ---------------------------------------------------------------------------
__global__ __launch_bounds__(256)
void bias_kernel(const float* __restrict__ Wih1, const float* __restrict__ bdec,
                 const float* __restrict__ bih1, const float* __restrict__ bhh1,
                 const float* __restrict__ bih2, const float* __restrict__ bhh2,
                 const float* __restrict__ bih3, const float* __restrict__ bhh3,
                 float* __restrict__ bc_gt, float* __restrict__ bc_ng,
                 float* __restrict__ bc2, float* __restrict__ bc3)
{
    const int j = blockIdx.x * 256 + threadIdx.x;
    if (j >= GG) return;
    const float s1 = bih1[j] + bhh1[j];
    float cb = 0.f;
    for (int m = 0; m < INPUT; ++m) cb += Wih1[(size_t)j * INPUT + m] * bdec[m];
    bc_gt[j] = s1;
    bc_ng[j] = s1 + cb;
    bc2[j] = bih2[j] + bhh2[j];
    bc3[j] = bih3[j] + bhh3[j];
}

// ---------------------------------------------------------------------------
// One timestep. grid 1024: WG owns unit u=wg. block 256 = 32 b x 8 k-slices
// of 128 halves. Six fp16 matrices passed as SEPARATE args (SGPR bases) +
// 4 shared VGPR byte-offsets off[g] — r5's pw[4][6] VGPR pointer array
// caused a 64-VGPR spill (1 GB scratch writes/dispatch); this is the fix.
// ---------------------------------------------------------------------------
template <bool USE_GT>
__global__ __launch_bounds__(256, 4)
void phase_kernel(const float* __restrict__ seq, const float* __restrict__ Wih1f,
                  const _Float16* __restrict__ Whh1h, const _Float16* __restrict__ Wih2h,
                  const _Float16* __restrict__ Whh2h, const _Float16* __restrict__ Wih3h,
                  const _Float16* __restrict__ Whh3h, const _Float16* __restrict__ Wcombh,
                  const _Float16* __restrict__ Wdec16, const float* __restrict__ bdec,
                  const float* __restrict__ bc_gt, const float* __restrict__ bc_ng,
                  const float* __restrict__ bc2, const float* __restrict__ bc3,
                  const unsigned int* __restrict__ h16r, _Float16* __restrict__ h16w,
                  float* __restrict__ cstT, float* __restrict__ outp, int t)
{
    __shared__ float red[4][12][BB];
    __shared__ float dpart[4][BB];

    const int tid = threadIdx.x;
    const int wg  = blockIdx.x;          // hidden unit u
    const int b   = tid & 31;
    const int cg  = tid >> 5;            // k-slice 0..7
    const int k0  = cg << 7;             // [k0, k0+128) halves

    const bool do_gates = (t < TT);
    const bool do_dec   = (t >= 1) && (wg < OUTC);

    float acc[12];
#pragma unroll
    for (int i = 0; i < 12; ++i) acc[i] = 0.f;
    float dec = 0.f;

    if (do_gates) {
        if (USE_GT) {
            // x-part (fp32): rows g*1024+u of Wih1, x = seq[b, t, :]
            for (int kq = cg; kq < 33; kq += 8) {
                const float4 xq = *(const float4*)&seq[(size_t)b * (TT * INPUT) +
                                                       (size_t)t * INPUT + (kq << 2)];
#pragma unroll
                for (int g = 0; g < 4; ++g) {
                    const float4 w = *(const float4*)&Wih1f[((g << 10) + wg) * INPUT + (kq << 2)];
                    acc[g] += w.x * xq.x + w.y * xq.y + w.z * xq.z + w.w * xq.w;
                }
            }
        }

        // 4 shared byte-offsets: row g*1024+wg, col k0, 2 B/half
        int off[4];
#pragma unroll
        for (int g = 0; g < 4; ++g)
            off[g] = ((((g << 10) + wg) << 10) + k0) << 1;
        const int doff = (((wg << 10) + k0) << 1);
        const unsigned int* hb = h16r + (size_t)(k0 >> 1) * SW + b;

#pragma unroll 2
        for (int it = 0; it < 16; ++it) {
            unsigned int hp0[4], hp1[4], hp2[4];
            const unsigned int* hq = hb + (it << 2) * SW;
#pragma unroll
            for (int p = 0; p < 4; ++p) {
                hp0[p] = hq[p * SW];
                hp1[p] = hq[p * SW + 32];
                hp2[p] = hq[p * SW + 64];
            }
            const int kb = it << 4;
#pragma unroll
            for (int g = 0; g < 4; ++g) {
                const int o = off[g] + kb;
                acc[g]     = dot2x4(ldw16(Whh1h, o), hp0, acc[g]);
                if (!USE_GT)
                    acc[g] = dot2x4(ldw16(Wcombh, o), hp2, acc[g]);
                acc[4 + g] = dot2x4(ldw16(Wih2h, o), hp0, acc[4 + g]);
                acc[4 + g] = dot2x4(ldw16(Whh2h, o), hp1, acc[4 + g]);
                acc[8 + g] = dot2x4(ldw16(Wih3h, o), hp1, acc[8 + g]);
                acc[8 + g] = dot2x4(ldw16(Whh3h, o), hp2, acc[8 + g]);
            }
            if (do_dec) dec = dot2x4(ldw16(Wdec16, doff + kb), hp2, dec);
        }
    } else if (do_dec) {
        const int doff = (((wg << 10) + k0) << 1);
        const unsigned int* hb = h16r + (size_t)(k0 >> 1) * SW + b;
#pragma unroll 2
        for (int it = 0; it < 16; ++it) {
            unsigned int hp2[4];
            const unsigned int* hq = hb + (it << 2) * SW;
#pragma unroll
            for (int p = 0; p < 4; ++p) hp2[p] = hq[p * SW + 64];
            dec = dot2x4(ldw16(Wdec16, doff + (it << 4)), hp2, dec);
        }
    }

    // pre-reduce k-slice pairs within each wave (lanes l, l^32 share b)
    if (do_gates) {
#pragma unroll
        for (int i = 0; i < 12; ++i) acc[i] += __shfl_xor(acc[i], 32);
        if (!(cg & 1)) {
            const int s = cg >> 1;
#pragma unroll
            for (int i = 0; i < 12; ++i) red[s][i][b] = acc[i];
        }
    }
    if (do_dec) {
        dec += __shfl_xor(dec, 32);
        if (!(cg & 1)) dpart[cg >> 1][b] = dec;
    }
    __syncthreads();

    if (do_gates && tid < 96) {
        const int cell = tid >> 5;
        const int bb = tid & 31;
        float gate[4];
#pragma unroll
        for (int g = 0; g < 4; ++g) {
            float s = 0.f;
#pragma unroll
            for (int sl = 0; sl < 4; ++sl) s += red[sl][cell * 4 + g][bb];
            gate[g] = s;
        }
        const float* bias = (cell == 0) ? (USE_GT ? bc_gt : bc_ng)
                                        : ((cell == 1) ? bc2 : bc3);
        const float gi = gate[0] + bias[wg];
        const float gf = gate[1] + bias[HH + wg];
        const float gg = gate[2] + bias[2 * HH + wg];
        const float go = gate[3] + bias[3 * HH + wg];
        const int si = wg * SW + cell * 32 + bb;
        const float cold = cstT[si];
        const float is = 1.f / (1.f + expf(-gi));
        const float fs = 1.f / (1.f + expf(-gf));
        const float os = 1.f / (1.f + expf(-go));
        const float cn = fs * cold + is * tanhf(gg);
        const float hn = os * tanhf(cn);
        cstT[si] = cn;
        // packed-pair fp16 h: word (u>>1), half (u&1)
        h16w[(((wg >> 1) * SW) + cell * 32 + bb) * 2 + (wg & 1)] = (_Float16)hn;
    }
    if (do_dec && tid < BB) {
        float s = 0.f;
#pragma unroll
        for (int sl = 0; sl < 4; ++sl) s += dpart[sl][tid];
        outp[(size_t)tid * (TT * OUTC) + (size_t)(t - 1) * OUTC + wg] = s + bdec[wg];
    }
}

// ---------------------------------------------------------------------------
extern "C" void kernel_launch(void* const* d_in, const int* in_sizes, int n_in,
                              void* d_out, int out_size, void* d_ws, size_t ws_size,
                              hipStream_t stream)
{
    const float* seq  = (const float*)d_in[0];
    const float* Wih1 = (const float*)d_in[1];
    const float* Whh1 = (const float*)d_in[2];
    const float* bih1 = (const float*)d_in[3];
    const float* bhh1 = (const float*)d_in[4];
    const float* Wih2 = (const float*)d_in[5];
    const float* Whh2 = (const float*)d_in[6];
    const float* bih2 = (const float*)d_in[7];
    const float* bhh2 = (const float*)d_in[8];
    const float* Wih3 = (const float*)d_in[9];
    const float* Whh3 = (const float*)d_in[10];
    const float* bih3 = (const float*)d_in[11];
    const float* bhh3 = (const float*)d_in[12];
    const float* Wdec = (const float*)d_in[13];
    const float* bdec = (const float*)d_in[14];
    float* outp = (float*)d_out;
    char* wsb   = (char*)d_ws;

    // ws layout (bytes)
    _Float16* W16    = (_Float16*)(wsb);                       // 6 x 8,388,608
    _Float16* Wdec16 = (_Float16*)(wsb + 50331648);            // 270,336
    float*    bc_gt  = (float*)(wsb + 50601984);               // 4 x 16,384
    float*    bc_ng  = bc_gt + GG;
    float*    bc2    = bc_ng + GG;
    float*    bc3    = bc2 + GG;
    char*     h16b   = wsb + 50667520;                         // 2 x 196,608
    float*    cstT   = (float*)(wsb + 51060736);               // 393,216

    _Float16* Whh1h  = W16 + 0 * (size_t)MH;
    _Float16* Wih2h  = W16 + 1 * (size_t)MH;
    _Float16* Whh2h  = W16 + 2 * (size_t)MH;
    _Float16* Wih3h  = W16 + 3 * (size_t)MH;
    _Float16* Whh3h  = W16 + 4 * (size_t)MH;
    _Float16* Wcombh = W16 + 5 * (size_t)MH;

    // zero h ping-pong (fp16 0x0000) + c state
    hipMemsetAsync(h16b, 0, 2 * 196608 + 393216, stream);

    conv_kernel<<<dim3(2048), dim3(256), 0, stream>>>(Whh1, Whh1h, MH / 4);
    conv_kernel<<<dim3(2048), dim3(256), 0, stream>>>(Wih2, Wih2h, MH / 4);
    conv_kernel<<<dim3(2048), dim3(256), 0, stream>>>(Whh2, Whh2h, MH / 4);
    conv_kernel<<<dim3(2048), dim3(256), 0, stream>>>(Wih3, Wih3h, MH / 4);
    conv_kernel<<<dim3(2048), dim3(256), 0, stream>>>(Whh3, Whh3h, MH / 4);
    conv_kernel<<<dim3(132),  dim3(256), 0, stream>>>(Wdec, Wdec16, (OUTC * HH) / 4);
    comb_kernel<<<dim3(1024), dim3(256), 0, stream>>>(Wih1, Wdec, Wcombh);
    bias_kernel<<<dim3(16), dim3(256), 0, stream>>>(Wih1, bdec, bih1, bhh1, bih2, bhh2,
                                                    bih3, bhh3, bc_gt, bc_ng, bc2, bc3);

    for (int t = 0; t <= TT; ++t) {
        const unsigned int* hr = (const unsigned int*)(h16b + (t & 1) * 196608);
        _Float16* hw = (_Float16*)(h16b + ((t + 1) & 1) * 196608);
        const bool gt = (t % 10) < 5;
        if (gt)
            phase_kernel<true><<<dim3(1024), dim3(256), 0, stream>>>(
                seq, Wih1, Whh1h, Wih2h, Whh2h, Wih3h, Whh3h, Wcombh, Wdec16, bdec,
                bc_gt, bc_ng, bc2, bc3, hr, hw, cstT, outp, t);
        else
            phase_kernel<false><<<dim3(1024), dim3(256), 0, stream>>>(
                seq, Wih1, Whh1h, Wih2h, Whh2h, Wih3h, Whh3h, Wcombh, Wdec16, bdec,
                bc_gt, bc_ng, bc2, bc3, hr, hw, cstT, outp, t);
    }
}

// Round 7
// 5363.016 us; speedup vs baseline: 6.6705x; 6.2150x over previous
//
#include <hip/hip_runtime.h>
#include <math.h>

#define BB    32
#define TT    100
#define INPUT 132
#define HH    1024
#define GG    4096
#define OUTC  132
#define SW    96                    // state row width: 3 cells * 32 batch
#define MH    4194304               // halves per 4096x1024 matrix

typedef _Float16 h2_t __attribute__((ext_vector_type(2)));
typedef _Float16 h4_t __attribute__((ext_vector_type(4)));

__device__ __forceinline__ float fdot2(unsigned int w, unsigned int h, float acc) {
    union { unsigned int u; h2_t h2; } uw, uh;
    uw.u = w; uh.u = h;
    return __builtin_amdgcn_fdot2(uw.h2, uh.h2, acc, false);
}
// weight uint4 (8 halves) dot packed-h words
__device__ __forceinline__ float dot2x4(uint4 wv, const unsigned int* hp, float a) {
    a = fdot2(wv.x, hp[0], a);
    a = fdot2(wv.y, hp[1], a);
    a = fdot2(wv.z, hp[2], a);
    a = fdot2(wv.w, hp[3], a);
    return a;
}
// SGPR-base + VGPR byte-offset load
__device__ __forceinline__ uint4 ldw16(const _Float16* __restrict__ p, int boff) {
    return *(const uint4*)((const char*)p + boff);
}

// ---------------------------------------------------------------------------
// fp32 -> fp16 weight conversion (n4 = n/4)
// ---------------------------------------------------------------------------
__global__ __launch_bounds__(256)
void conv_kernel(const float* __restrict__ src, _Float16* __restrict__ dst, int n4)
{
    for (int i = blockIdx.x * 256 + threadIdx.x; i < n4; i += gridDim.x * 256) {
        const float4 v = ((const float4*)src)[i];
        h4_t o; o.x = (_Float16)v.x; o.y = (_Float16)v.y;
        o.z = (_Float16)v.z; o.w = (_Float16)v.w;
        ((h4_t*)dst)[i] = o;
    }
}

// ---------------------------------------------------------------------------
// W_comb[j][k] = sum_m W_ih1[j][m] * W_dec[m][k]  (4096x1024), fp16 output
// ---------------------------------------------------------------------------
__global__ __launch_bounds__(256)
void comb_kernel(const float* __restrict__ Wih1, const float* __restrict__ Wdec,
                 _Float16* __restrict__ Wcomb16)
{
    __shared__ float wiT[INPUT][64];
    __shared__ float wd[INPUT][64];
    const int tid = threadIdx.x;
    const int jt = (blockIdx.x >> 4) << 6;
    const int kt = (blockIdx.x & 15) << 6;

    for (int i = tid; i < 64 * INPUT; i += 256) {
        const int j = i / INPUT, m = i % INPUT;
        wiT[m][j] = Wih1[(size_t)(jt + j) * INPUT + m];
    }
    for (int i = tid; i < INPUT * 64; i += 256) {
        const int m = i >> 6, k = i & 63;
        wd[m][k] = Wdec[(size_t)m * HH + kt + k];
    }
    __syncthreads();

    const int jl = (tid >> 4) << 2;
    const int kl = (tid & 15) << 2;
    float a[4][4];
#pragma unroll
    for (int x = 0; x < 4; ++x)
#pragma unroll
        for (int y = 0; y < 4; ++y) a[x][y] = 0.f;

    for (int m = 0; m < INPUT; ++m) {
        const float4 wj = *(const float4*)&wiT[m][jl];
        const float4 wk = *(const float4*)&wd[m][kl];
        a[0][0] += wj.x * wk.x; a[0][1] += wj.x * wk.y; a[0][2] += wj.x * wk.z; a[0][3] += wj.x * wk.w;
        a[1][0] += wj.y * wk.x; a[1][1] += wj.y * wk.y; a[1][2] += wj.y * wk.z; a[1][3] += wj.y * wk.w;
        a[2][0] += wj.z * wk.x; a[2][1] += wj.z * wk.y; a[2][2] += wj.z * wk.z; a[2][3] += wj.z * wk.w;
        a[3][0] += wj.w * wk.x; a[3][1] += wj.w * wk.y; a[3][2] += wj.w * wk.z; a[3][3] += wj.w * wk.w;
    }
#pragma unroll
    for (int jj = 0; jj < 4; ++jj) {
        h4_t v; v.x = (_Float16)a[jj][0]; v.y = (_Float16)a[jj][1];
        v.z = (_Float16)a[jj][2]; v.w = (_Float16)a[jj][3];
        *(h4_t*)&Wcomb16[(size_t)(jt + jl + jj) * HH + kt + kl] = v;
    }
}

// ---------------------------------------------------------------------------
// Bias precompute (fp32)
// ---------------------------------------------------------------------------
__global__ __launch_bounds__(256)
void bias_kernel(const float* __restrict__ Wih1, const float* __restrict__ bdec,
                 const float* __restrict__ bih1, const float* __restrict__ bhh1,
                 const float* __restrict__ bih2, const float* __restrict__ bhh2,
                 const float* __restrict__ bih3, const float* __restrict__ bhh3,
                 float* __restrict__ bc_gt, float* __restrict__ bc_ng,
                 float* __restrict__ bc2, float* __restrict__ bc3)
{
    const int j = blockIdx.x * 256 + threadIdx.x;
    if (j >= GG) return;
    const float s1 = bih1[j] + bhh1[j];
    float cb = 0.f;
    for (int m = 0; m < INPUT; ++m) cb += Wih1[(size_t)j * INPUT + m] * bdec[m];
    bc_gt[j] = s1;
    bc_ng[j] = s1 + cb;
    bc2[j] = bih2[j] + bhh2[j];
    bc3[j] = bih3[j] + bhh3[j];
}

// ---------------------------------------------------------------------------
// One timestep. grid 1024: WG owns unit u=wg. block 256 = 32 b x 8 k-slices
// of 128 halves. Six fp16 matrices as SEPARATE args (SGPR bases) + 4 shared
// VGPR byte-offsets.
// __launch_bounds__(256, 1): empirical law across r1/r4/r5/r6 — arg=4 budgets
// 64 VGPR (spill, 840 MB scratch/dispatch), arg=2 budgets 128, arg=1 leaves
// the allocator free (r4: 100 VGPR, no spill). Body needs ~120-130 live.
// #pragma unroll 1: cap in-flight loads at one iteration's 21x16B.
// ---------------------------------------------------------------------------
template <bool USE_GT>
__global__ __launch_bounds__(256, 1)
void phase_kernel(const float* __restrict__ seq, const float* __restrict__ Wih1f,
                  const _Float16* __restrict__ Whh1h, const _Float16* __restrict__ Wih2h,
                  const _Float16* __restrict__ Whh2h, const _Float16* __restrict__ Wih3h,
                  const _Float16* __restrict__ Whh3h, const _Float16* __restrict__ Wcombh,
                  const _Float16* __restrict__ Wdec16, const float* __restrict__ bdec,
                  const float* __restrict__ bc_gt, const float* __restrict__ bc_ng,
                  const float* __restrict__ bc2, const float* __restrict__ bc3,
                  const unsigned int* __restrict__ h16r, _Float16* __restrict__ h16w,
                  float* __restrict__ cstT, float* __restrict__ outp, int t)
{
    __shared__ float red[4][12][BB];
    __shared__ float dpart[4][BB];

    const int tid = threadIdx.x;
    const int wg  = blockIdx.x;          // hidden unit u
    const int b   = tid & 31;
    const int cg  = tid >> 5;            // k-slice 0..7
    const int k0  = cg << 7;             // [k0, k0+128) halves

    const bool do_gates = (t < TT);
    const bool do_dec   = (t >= 1) && (wg < OUTC);

    float acc[12];
#pragma unroll
    for (int i = 0; i < 12; ++i) acc[i] = 0.f;
    float dec = 0.f;

    if (do_gates) {
        if (USE_GT) {
            // x-part (fp32): rows g*1024+u of Wih1, x = seq[b, t, :]
            for (int kq = cg; kq < 33; kq += 8) {
                const float4 xq = *(const float4*)&seq[(size_t)b * (TT * INPUT) +
                                                       (size_t)t * INPUT + (kq << 2)];
#pragma unroll
                for (int g = 0; g < 4; ++g) {
                    const float4 w = *(const float4*)&Wih1f[((g << 10) + wg) * INPUT + (kq << 2)];
                    acc[g] += w.x * xq.x + w.y * xq.y + w.z * xq.z + w.w * xq.w;
                }
            }
        }

        // 4 shared byte-offsets: row g*1024+wg, col k0, 2 B/half
        int off[4];
#pragma unroll
        for (int g = 0; g < 4; ++g)
            off[g] = ((((g << 10) + wg) << 10) + k0) << 1;
        const int doff = (((wg << 10) + k0) << 1);
        const unsigned int* hb = h16r + (size_t)(k0 >> 1) * SW + b;

#pragma unroll 1
        for (int it = 0; it < 16; ++it) {
            unsigned int hp0[4], hp1[4], hp2[4];
            const unsigned int* hq = hb + (it << 2) * SW;
#pragma unroll
            for (int p = 0; p < 4; ++p) {
                hp0[p] = hq[p * SW];
                hp1[p] = hq[p * SW + 32];
                hp2[p] = hq[p * SW + 64];
            }
            const int kb = it << 4;
#pragma unroll
            for (int g = 0; g < 4; ++g) {
                const int o = off[g] + kb;
                acc[g]     = dot2x4(ldw16(Whh1h, o), hp0, acc[g]);
                if (!USE_GT)
                    acc[g] = dot2x4(ldw16(Wcombh, o), hp2, acc[g]);
                acc[4 + g] = dot2x4(ldw16(Wih2h, o), hp0, acc[4 + g]);
                acc[4 + g] = dot2x4(ldw16(Whh2h, o), hp1, acc[4 + g]);
                acc[8 + g] = dot2x4(ldw16(Wih3h, o), hp1, acc[8 + g]);
                acc[8 + g] = dot2x4(ldw16(Whh3h, o), hp2, acc[8 + g]);
            }
            if (do_dec) dec = dot2x4(ldw16(Wdec16, doff + kb), hp2, dec);
        }
    } else if (do_dec) {
        const int doff = (((wg << 10) + k0) << 1);
        const unsigned int* hb = h16r + (size_t)(k0 >> 1) * SW + b;
#pragma unroll 1
        for (int it = 0; it < 16; ++it) {
            unsigned int hp2[4];
            const unsigned int* hq = hb + (it << 2) * SW;
#pragma unroll
            for (int p = 0; p < 4; ++p) hp2[p] = hq[p * SW + 64];
            dec = dot2x4(ldw16(Wdec16, doff + (it << 4)), hp2, dec);
        }
    }

    // pre-reduce k-slice pairs within each wave (lanes l, l^32 share b)
    if (do_gates) {
#pragma unroll
        for (int i = 0; i < 12; ++i) acc[i] += __shfl_xor(acc[i], 32);
        if (!(cg & 1)) {
            const int s = cg >> 1;
#pragma unroll
            for (int i = 0; i < 12; ++i) red[s][i][b] = acc[i];
        }
    }
    if (do_dec) {
        dec += __shfl_xor(dec, 32);
        if (!(cg & 1)) dpart[cg >> 1][b] = dec;
    }
    __syncthreads();

    if (do_gates && tid < 96) {
        const int cell = tid >> 5;
        const int bb = tid & 31;
        float gate[4];
#pragma unroll
        for (int g = 0; g < 4; ++g) {
            float s = 0.f;
#pragma unroll
            for (int sl = 0; sl < 4; ++sl) s += red[sl][cell * 4 + g][bb];
            gate[g] = s;
        }
        const float* bias = (cell == 0) ? (USE_GT ? bc_gt : bc_ng)
                                        : ((cell == 1) ? bc2 : bc3);
        const float gi = gate[0] + bias[wg];
        const float gf = gate[1] + bias[HH + wg];
        const float gg = gate[2] + bias[2 * HH + wg];
        const float go = gate[3] + bias[3 * HH + wg];
        const int si = wg * SW + cell * 32 + bb;
        const float cold = cstT[si];
        const float is = 1.f / (1.f + expf(-gi));
        const float fs = 1.f / (1.f + expf(-gf));
        const float os = 1.f / (1.f + expf(-go));
        const float cn = fs * cold + is * tanhf(gg);
        const float hn = os * tanhf(cn);
        cstT[si] = cn;
        // packed-pair fp16 h: word (u>>1), half (u&1)
        h16w[(((wg >> 1) * SW) + cell * 32 + bb) * 2 + (wg & 1)] = (_Float16)hn;
    }
    if (do_dec && tid < BB) {
        float s = 0.f;
#pragma unroll
        for (int sl = 0; sl < 4; ++sl) s += dpart[sl][tid];
        outp[(size_t)tid * (TT * OUTC) + (size_t)(t - 1) * OUTC + wg] = s + bdec[wg];
    }
}

// ---------------------------------------------------------------------------
extern "C" void kernel_launch(void* const* d_in, const int* in_sizes, int n_in,
                              void* d_out, int out_size, void* d_ws, size_t ws_size,
                              hipStream_t stream)
{
    const float* seq  = (const float*)d_in[0];
    const float* Wih1 = (const float*)d_in[1];
    const float* Whh1 = (const float*)d_in[2];
    const float* bih1 = (const float*)d_in[3];
    const float* bhh1 = (const float*)d_in[4];
    const float* Wih2 = (const float*)d_in[5];
    const float* Whh2 = (const float*)d_in[6];
    const float* bih2 = (const float*)d_in[7];
    const float* bhh2 = (const float*)d_in[8];
    const float* Wih3 = (const float*)d_in[9];
    const float* Whh3 = (const float*)d_in[10];
    const float* bih3 = (const float*)d_in[11];
    const float* bhh3 = (const float*)d_in[12];
    const float* Wdec = (const float*)d_in[13];
    const float* bdec = (const float*)d_in[14];
    float* outp = (float*)d_out;
    char* wsb   = (char*)d_ws;

    // ws layout (bytes)
    _Float16* W16    = (_Float16*)(wsb);                       // 6 x 8,388,608
    _Float16* Wdec16 = (_Float16*)(wsb + 50331648);            // 270,336
    float*    bc_gt  = (float*)(wsb + 50601984);               // 4 x 16,384
    float*    bc_ng  = bc_gt + GG;
    float*    bc2    = bc_ng + GG;
    float*    bc3    = bc2 + GG;
    char*     h16b   = wsb + 50667520;                         // 2 x 196,608
    float*    cstT   = (float*)(wsb + 51060736);               // 393,216

    _Float16* Whh1h  = W16 + 0 * (size_t)MH;
    _Float16* Wih2h  = W16 + 1 * (size_t)MH;
    _Float16* Whh2h  = W16 + 2 * (size_t)MH;
    _Float16* Wih3h  = W16 + 3 * (size_t)MH;
    _Float16* Whh3h  = W16 + 4 * (size_t)MH;
    _Float16* Wcombh = W16 + 5 * (size_t)MH;

    // zero h ping-pong (fp16 0x0000) + c state
    hipMemsetAsync(h16b, 0, 2 * 196608 + 393216, stream);

    conv_kernel<<<dim3(2048), dim3(256), 0, stream>>>(Whh1, Whh1h, MH / 4);
    conv_kernel<<<dim3(2048), dim3(256), 0, stream>>>(Wih2, Wih2h, MH / 4);
    conv_kernel<<<dim3(2048), dim3(256), 0, stream>>>(Whh2, Whh2h, MH / 4);
    conv_kernel<<<dim3(2048), dim3(256), 0, stream>>>(Wih3, Wih3h, MH / 4);
    conv_kernel<<<dim3(2048), dim3(256), 0, stream>>>(Whh3, Whh3h, MH / 4);
    conv_kernel<<<dim3(132),  dim3(256), 0, stream>>>(Wdec, Wdec16, (OUTC * HH) / 4);
    comb_kernel<<<dim3(1024), dim3(256), 0, stream>>>(Wih1, Wdec, Wcombh);
    bias_kernel<<<dim3(16), dim3(256), 0, stream>>>(Wih1, bdec, bih1, bhh1, bih2, bhh2,
                                                    bih3, bhh3, bc_gt, bc_ng, bc2, bc3);

    for (int t = 0; t <= TT; ++t) {
        const unsigned int* hr = (const unsigned int*)(h16b + (t & 1) * 196608);
        _Float16* hw = (_Float16*)(h16b + ((t + 1) & 1) * 196608);
        const bool gt = (t % 10) < 5;
        if (gt)
            phase_kernel<true><<<dim3(1024), dim3(256), 0, stream>>>(
                seq, Wih1, Whh1h, Wih2h, Whh2h, Wih3h, Whh3h, Wcombh, Wdec16, bdec,
                bc_gt, bc_ng, bc2, bc3, hr, hw, cstT, outp, t);
        else
            phase_kernel<false><<<dim3(1024), dim3(256), 0, stream>>>(
                seq, Wih1, Whh1h, Wih2h, Whh2h, Wih3h, Whh3h, Wcombh, Wdec16, bdec,
                bc_gt, bc_ng, bc2, bc3, hr, hw, cstT, outp, t);
    }
}

// Round 9
// 2569.258 us; speedup vs baseline: 13.9238x; 2.0874x over previous
//
#include <hip/hip_runtime.h>
#include <math.h>

#define BB    32
#define TT    100
#define INPUT 132
#define HH    1024
#define GG    4096
#define OUTC  132
#define SW    96                    // state row width: 3 cells * 32 batch

typedef _Float16 h2_t __attribute__((ext_vector_type(2)));
typedef _Float16 h4_t __attribute__((ext_vector_type(4)));

#define AS1 __attribute__((address_space(1)))
#define AS3 __attribute__((address_space(3)))

__device__ __forceinline__ float fdot2(unsigned int w, unsigned int h, float acc) {
    union { unsigned int u; h2_t h2; } uw, uh;
    uw.u = w; uh.u = h;
    return __builtin_amdgcn_fdot2(uw.h2, uh.h2, acc, false);
}
__device__ __forceinline__ float dot2x4(uint4 wv, const unsigned int* hp, float a) {
    a = fdot2(wv.x, hp[0], a);
    a = fdot2(wv.y, hp[1], a);
    a = fdot2(wv.z, hp[2], a);
    a = fdot2(wv.w, hp[3], a);
    return a;
}
__device__ __forceinline__ void stage16(const void* g, void* l) {
    __builtin_amdgcn_global_load_lds((const AS1 void*)g, (AS3 void*)l, 16, 0, 0);
}
__device__ __forceinline__ h4_t cvt4(float4 v) {
    h4_t o; o.x = (_Float16)v.x; o.y = (_Float16)v.y;
    o.z = (_Float16)v.z; o.w = (_Float16)v.w;
    return o;
}

// ---------------------------------------------------------------------------
// Pack 5 recurrent matrices into P[u][c][24] (fp16): chunk c = 8 halves of k,
// row r = g*5 + m (m: Whh1,Wih2,Whh2,Wih3,Whh3); rows 20..23 = Wcomb (below).
// ---------------------------------------------------------------------------
__global__ __launch_bounds__(256)
void pack5_kernel(const float* __restrict__ Whh1, const float* __restrict__ Wih2,
                  const float* __restrict__ Whh2, const float* __restrict__ Wih3,
                  const float* __restrict__ Whh3, _Float16* __restrict__ P)
{
    const int total = HH * 128 * 20;
    for (int i = blockIdx.x * 256 + threadIdx.x; i < total; i += gridDim.x * 256) {
        const int r = i % 20;
        const int c = (i / 20) & 127;
        const int u = i / (20 * 128);
        const int g = r / 5, m = r % 5;
        const float* src = (m == 0) ? Whh1 : (m == 1) ? Wih2 : (m == 2) ? Whh2
                         : (m == 3) ? Wih3 : Whh3;
        const float* s = src + (((size_t)((g << 10) + u)) << 10) + (c << 3);
        union { uint4 q; h4_t h[2]; } o;
        o.h[0] = cvt4(*(const float4*)s);
        o.h[1] = cvt4(*(const float4*)(s + 4));
        *(uint4*)(P + ((size_t)(u * 128 + c) * 24 + r) * 8) = o.q;
    }
}

// ---------------------------------------------------------------------------
// W_comb = W_ih1 @ W_dec (4096x1024) -> packed rows 20+g of P, fp16
// ---------------------------------------------------------------------------
__global__ __launch_bounds__(256)
void comb_kernel(const float* __restrict__ Wih1, const float* __restrict__ Wdec,
                 _Float16* __restrict__ P)
{
    __shared__ float wiT[INPUT][64];
    __shared__ float wd[INPUT][64];
    const int tid = threadIdx.x;
    const int jt = (blockIdx.x >> 4) << 6;
    const int kt = (blockIdx.x & 15) << 6;

    for (int i = tid; i < 64 * INPUT; i += 256) {
        const int j = i / INPUT, m = i % INPUT;
        wiT[m][j] = Wih1[(size_t)(jt + j) * INPUT + m];
    }
    for (int i = tid; i < INPUT * 64; i += 256) {
        const int m = i >> 6, k = i & 63;
        wd[m][k] = Wdec[(size_t)m * HH + kt + k];
    }
    __syncthreads();

    const int jl = (tid >> 4) << 2;
    const int kl = (tid & 15) << 2;
    float a[4][4];
#pragma unroll
    for (int x = 0; x < 4; ++x)
#pragma unroll
        for (int y = 0; y < 4; ++y) a[x][y] = 0.f;

    for (int m = 0; m < INPUT; ++m) {
        const float4 wj = *(const float4*)&wiT[m][jl];
        const float4 wk = *(const float4*)&wd[m][kl];
        a[0][0] += wj.x * wk.x; a[0][1] += wj.x * wk.y; a[0][2] += wj.x * wk.z; a[0][3] += wj.x * wk.w;
        a[1][0] += wj.y * wk.x; a[1][1] += wj.y * wk.y; a[1][2] += wj.y * wk.z; a[1][3] += wj.y * wk.w;
        a[2][0] += wj.z * wk.x; a[2][1] += wj.z * wk.y; a[2][2] += wj.z * wk.z; a[2][3] += wj.z * wk.w;
        a[3][0] += wj.w * wk.x; a[3][1] += wj.w * wk.y; a[3][2] += wj.w * wk.z; a[3][3] += wj.w * wk.w;
    }
#pragma unroll
    for (int jj = 0; jj < 4; ++jj) {
        const int j = jt + jl + jj;
        const int u = j & 1023, g = j >> 10;
        const int k = kt + kl;
        const int c = k >> 3, sub = k & 7;
        h4_t v; v.x = (_Float16)a[jj][0]; v.y = (_Float16)a[jj][1];
        v.z = (_Float16)a[jj][2]; v.w = (_Float16)a[jj][3];
        *(h4_t*)((char*)P + ((((size_t)u * 128 + c) * 24 + 20 + g) << 4) + (sub << 1)) = v;
    }
}

// ---------------------------------------------------------------------------
// fp32 -> fp16 conversion (Wdec)
// ---------------------------------------------------------------------------
__global__ __launch_bounds__(256)
void conv_kernel(const float* __restrict__ src, _Float16* __restrict__ dst, int n4)
{
    for (int i = blockIdx.x * 256 + threadIdx.x; i < n4; i += gridDim.x * 256) {
        const float4 v = ((const float4*)src)[i];
        ((h4_t*)dst)[i] = cvt4(v);
    }
}

// ---------------------------------------------------------------------------
// Bias precompute (fp32)
// ---------------------------------------------------------------------------
__global__ __launch_bounds__(256)
void bias_kernel(const float* __restrict__ Wih1, const float* __restrict__ bdec,
                 const float* __restrict__ bih1, const float* __restrict__ bhh1,
                 const float* __restrict__ bih2, const float* __restrict__ bhh2,
                 const float* __restrict__ bih3, const float* __restrict__ bhh3,
                 float* __restrict__ bc_gt, float* __restrict__ bc_ng,
                 float* __restrict__ bc2, float* __restrict__ bc3)
{
    const int j = blockIdx.x * 256 + threadIdx.x;
    if (j >= GG) return;
    const float s1 = bih1[j] + bhh1[j];
    float cb = 0.f;
    for (int m = 0; m < INPUT; ++m) cb += Wih1[(size_t)j * INPUT + m] * bdec[m];
    bc_gt[j] = s1;
    bc_ng[j] = s1 + cb;
    bc2[j] = bih2[j] + bhh2[j];
    bc3[j] = bih3[j] + bhh3[j];
}

// ---------------------------------------------------------------------------
// One timestep. grid 1024: WG owns unit u=wg. block 256 = 32 b x 8 k-slices.
// Weights: packed P[u][c][24], DMA'd global->LDS (wbuf double buffer).
// Wave w stages AND consumes cg in {2w, 2w+1} -> no barriers, per-wave vmcnt.
// vmcnt COUNTS INSTRUCTIONS PER WAVE, retiring in order: per iter a wave
// issues 12 h-loads + (0|1) dv + 1 stage = 13-14 newer ops than the stage
// that filled the buffer being read -> vmcnt(13) is the max safe count
// (r8's 40/48 was a race, counted per-lane by mistake).
// ---------------------------------------------------------------------------
template <bool USE_GT>
__global__ __launch_bounds__(256, 1)
void phase_kernel(const float* __restrict__ seq, const float* __restrict__ Wih1f,
                  const _Float16* __restrict__ Ppk,
                  const _Float16* __restrict__ Wdec16, const float* __restrict__ bdec,
                  const float* __restrict__ bc_gt, const float* __restrict__ bc_ng,
                  const float* __restrict__ bc2, const float* __restrict__ bc3,
                  const unsigned int* __restrict__ h16r, _Float16* __restrict__ h16w,
                  float* __restrict__ cstT, float* __restrict__ outp, int t)
{
    constexpr int ROWS = USE_GT ? 20 : 24;   // gt steps skip Wcomb rows
    __shared__ uint4 wbuf[2][4][64];         // [buf][wave][lane] 16B slots
    __shared__ float red[4][12][BB];
    __shared__ float dpart[4][BB];

    const int tid = threadIdx.x;
    const int wg  = blockIdx.x;              // hidden unit u
    const int b   = tid & 31;
    const int cg  = tid >> 5;                // k-slice 0..7 (128 halves each)

    const bool do_gates = (t < TT);
    const bool do_dec   = (t >= 1) && (wg < OUTC);

    float acc[12];
#pragma unroll
    for (int i = 0; i < 12; ++i) acc[i] = 0.f;
    float dec = 0.f;

    if (do_gates) {
        if (USE_GT) {
            for (int kq = cg; kq < 33; kq += 8) {
                const float4 xq = *(const float4*)&seq[(size_t)b * (TT * INPUT) +
                                                       (size_t)t * INPUT + (kq << 2)];
#pragma unroll
                for (int g = 0; g < 4; ++g) {
                    const float4 w = *(const float4*)&Wih1f[((g << 10) + wg) * INPUT + (kq << 2)];
                    acc[g] += w.x * xq.x + w.y * xq.y + w.z * xq.z + w.w * xq.w;
                }
            }
        }

        // ---- staging role: wave w stages cg = 2w, 2w+1 (slot index == lane)
        const int w  = tid >> 6;
        const int l  = tid & 63;
        const bool st_act = l < 2 * ROWS;
        const int cg_s = (w << 1) + (l >= ROWS ? 1 : 0);
        const int r_s  = (l >= ROWS) ? l - ROWS : l;
        const _Float16* gsrc0 = Ppk +
            (((size_t)wg * 128 + (size_t)cg_s * 16) * 24 + r_s) * 8;

        const unsigned int* hb = h16r + (size_t)(cg << 6) * SW + b;
        const int dbase = (wg << 10) + (cg << 7);

        // prologue: stage it=0
        if (st_act) stage16(gsrc0, &wbuf[0][w][0]);

#pragma unroll 1
        for (int it = 0; it < 16; ++it) {
            unsigned int hp0[4], hp1[4], hp2[4];
            const unsigned int* hq = hb + (it << 2) * SW;
#pragma unroll
            for (int p = 0; p < 4; ++p) {
                hp0[p] = hq[p * SW];
                hp1[p] = hq[p * SW + 32];
                hp2[p] = hq[p * SW + 64];
            }
            uint4 dv;
            if (do_dec) dv = *(const uint4*)(Wdec16 + dbase + (it << 3));

            if (it < 15) {
                if (st_act) stage16(gsrc0 + (size_t)(it + 1) * 192, &wbuf[(it + 1) & 1][w][0]);
                // 13 VMEM ops (12 h + stage(it+1)) are newer than stage(it);
                // dv may add one more. vmcnt<=13 => stage(it) retired.
                asm volatile("s_waitcnt vmcnt(13)" ::: "memory");
            } else {
                asm volatile("s_waitcnt vmcnt(0)" ::: "memory");
            }

            const uint4* wl = (const uint4*)&wbuf[it & 1][cg >> 1][(cg & 1) * ROWS];
#pragma unroll
            for (int g = 0; g < 4; ++g) {
                acc[g]     = dot2x4(wl[g * 5 + 0], hp0, acc[g]);       // Whh1
                acc[4 + g] = dot2x4(wl[g * 5 + 1], hp0, acc[4 + g]);   // Wih2
                acc[4 + g] = dot2x4(wl[g * 5 + 2], hp1, acc[4 + g]);   // Whh2
                acc[8 + g] = dot2x4(wl[g * 5 + 3], hp1, acc[8 + g]);   // Wih3
                acc[8 + g] = dot2x4(wl[g * 5 + 4], hp2, acc[8 + g]);   // Whh3
                if (!USE_GT)
                    acc[g] = dot2x4(wl[20 + g], hp2, acc[g]);          // Wcomb
            }
            if (do_dec) dec = dot2x4(dv, hp2, dec);
        }
    } else if (do_dec) {
        const int dbase = (wg << 10) + (cg << 7);
        const unsigned int* hb = h16r + (size_t)(cg << 6) * SW + b;
#pragma unroll 1
        for (int it = 0; it < 16; ++it) {
            unsigned int hp2[4];
            const unsigned int* hq = hb + (it << 2) * SW;
#pragma unroll
            for (int p = 0; p < 4; ++p) hp2[p] = hq[p * SW + 64];
            dec = dot2x4(*(const uint4*)(Wdec16 + dbase + (it << 3)), hp2, dec);
        }
    }

    // pre-reduce k-slice pairs within each wave (lanes l, l^32 share b)
    if (do_gates) {
#pragma unroll
        for (int i = 0; i < 12; ++i) acc[i] += __shfl_xor(acc[i], 32);
        if (!(cg & 1)) {
            const int s = cg >> 1;
#pragma unroll
            for (int i = 0; i < 12; ++i) red[s][i][b] = acc[i];
        }
    }
    if (do_dec) {
        dec += __shfl_xor(dec, 32);
        if (!(cg & 1)) dpart[cg >> 1][b] = dec;
    }
    __syncthreads();

    if (do_gates && tid < 96) {
        const int cell = tid >> 5;
        const int bb = tid & 31;
        float gate[4];
#pragma unroll
        for (int g = 0; g < 4; ++g) {
            float s = 0.f;
#pragma unroll
            for (int sl = 0; sl < 4; ++sl) s += red[sl][cell * 4 + g][bb];
            gate[g] = s;
        }
        const float* bias = (cell == 0) ? (USE_GT ? bc_gt : bc_ng)
                                        : ((cell == 1) ? bc2 : bc3);
        const float gi = gate[0] + bias[wg];
        const float gf = gate[1] + bias[HH + wg];
        const float gg = gate[2] + bias[2 * HH + wg];
        const float go = gate[3] + bias[3 * HH + wg];
        const int si = wg * SW + cell * 32 + bb;
        const float cold = cstT[si];
        const float is = 1.f / (1.f + expf(-gi));
        const float fs = 1.f / (1.f + expf(-gf));
        const float os = 1.f / (1.f + expf(-go));
        const float cn = fs * cold + is * tanhf(gg);
        const float hn = os * tanhf(cn);
        cstT[si] = cn;
        h16w[(((wg >> 1) * SW) + cell * 32 + bb) * 2 + (wg & 1)] = (_Float16)hn;
    }
    if (do_dec && tid < BB) {
        float s = 0.f;
#pragma unroll
        for (int sl = 0; sl < 4; ++sl) s += dpart[sl][tid];
        outp[(size_t)tid * (TT * OUTC) + (size_t)(t - 1) * OUTC + wg] = s + bdec[wg];
    }
}

// ---------------------------------------------------------------------------
extern "C" void kernel_launch(void* const* d_in, const int* in_sizes, int n_in,
                              void* d_out, int out_size, void* d_ws, size_t ws_size,
                              hipStream_t stream)
{
    const float* seq  = (const float*)d_in[0];
    const float* Wih1 = (const float*)d_in[1];
    const float* Whh1 = (const float*)d_in[2];
    const float* bih1 = (const float*)d_in[3];
    const float* bhh1 = (const float*)d_in[4];
    const float* Wih2 = (const float*)d_in[5];
    const float* Whh2 = (const float*)d_in[6];
    const float* bih2 = (const float*)d_in[7];
    const float* bhh2 = (const float*)d_in[8];
    const float* Wih3 = (const float*)d_in[9];
    const float* Whh3 = (const float*)d_in[10];
    const float* bih3 = (const float*)d_in[11];
    const float* bhh3 = (const float*)d_in[12];
    const float* Wdec = (const float*)d_in[13];
    const float* bdec = (const float*)d_in[14];
    float* outp = (float*)d_out;
    char* wsb   = (char*)d_ws;

    // ws layout (bytes)
    _Float16* Ppk    = (_Float16*)(wsb);                       // 50,331,648
    _Float16* Wdec16 = (_Float16*)(wsb + 50331648);            // 270,336
    float*    bc_gt  = (float*)(wsb + 50601984);               // 4 x 16,384
    float*    bc_ng  = bc_gt + GG;
    float*    bc2    = bc_ng + GG;
    float*    bc3    = bc2 + GG;
    char*     h16b   = wsb + 50667520;                         // 2 x 196,608
    float*    cstT   = (float*)(wsb + 51060736);               // 393,216

    // zero h ping-pong (fp16 0x0000) + c state
    hipMemsetAsync(h16b, 0, 2 * 196608 + 393216, stream);

    pack5_kernel<<<dim3(2048), dim3(256), 0, stream>>>(Whh1, Wih2, Whh2, Wih3, Whh3, Ppk);
    comb_kernel<<<dim3(1024), dim3(256), 0, stream>>>(Wih1, Wdec, Ppk);
    conv_kernel<<<dim3(132),  dim3(256), 0, stream>>>(Wdec, Wdec16, (OUTC * HH) / 4);
    bias_kernel<<<dim3(16), dim3(256), 0, stream>>>(Wih1, bdec, bih1, bhh1, bih2, bhh2,
                                                    bih3, bhh3, bc_gt, bc_ng, bc2, bc3);

    for (int t = 0; t <= TT; ++t) {
        const unsigned int* hr = (const unsigned int*)(h16b + (t & 1) * 196608);
        _Float16* hw = (_Float16*)(h16b + ((t + 1) & 1) * 196608);
        const bool gt = (t % 10) < 5;
        if (gt)
            phase_kernel<true><<<dim3(1024), dim3(256), 0, stream>>>(
                seq, Wih1, Ppk, Wdec16, bdec, bc_gt, bc_ng, bc2, bc3,
                hr, hw, cstT, outp, t);
        else
            phase_kernel<false><<<dim3(1024), dim3(256), 0, stream>>>(
                seq, Wih1, Ppk, Wdec16, bdec, bc_gt, bc_ng, bc2, bc3,
                hr, hw, cstT, outp, t);
    }
}